// Round 2
// baseline (19387.839 us; speedup 1.0000x reference)
//
#include <hip/hip_runtime.h>
#include <cmath>

constexpr int NB = 128;     // batch
constexpr int NS = 384;     // seq len
constexpr int NH = 384;     // hidden = input dim
constexpr int NZCOL = 3456; // 4H (gate p) + H (mv) + 4H (gate q)
constexpr int NG4 = 1536;
constexpr int GBLK = 240;   // persistent grid size
constexpr int KSL = 48;     // K-slice per GEMM task
constexpr int NKS = 8;      // 384 / 48

__device__ __forceinline__ double clampd(double x, double lo, double hi){ return fmin(fmax(x,lo),hi); }
__device__ __forceinline__ double artanh_(double x){ return atanh(clampd(x, -1.0 + 1e-7, 1.0 - 1e-7)); }
__device__ __forceinline__ double normclip(double s){ return sqrt(fmax(s, 1e-15)); }
__device__ __forceinline__ double wredsumd(double v){
  #pragma unroll
  for (int off = 32; off; off >>= 1) v += __shfl_xor(v, off, 64);
  return v;
}

// ---------------- grid barrier (agent-scope, generation-counting) ----------------
// Safe given all GBLK blocks are co-resident (validated host-side before launch).
__device__ __forceinline__ void gridbar(unsigned* bar){
  __syncthreads();
  if (threadIdx.x == 0){
    __threadfence();   // release: this block's stores -> coherent point
    unsigned gen = __hip_atomic_load(&bar[1], __ATOMIC_ACQUIRE, __HIP_MEMORY_SCOPE_AGENT);
    unsigned arr = __hip_atomic_fetch_add(&bar[0], 1u, __ATOMIC_ACQ_REL, __HIP_MEMORY_SCOPE_AGENT);
    if (arr == (unsigned)(GBLK - 1)){
      __hip_atomic_store(&bar[0], 0u, __ATOMIC_RELAXED, __HIP_MEMORY_SCOPE_AGENT);
      __hip_atomic_fetch_add(&bar[1], 1u, __ATOMIC_RELEASE, __HIP_MEMORY_SCOPE_AGENT);
    } else {
      while (__hip_atomic_load(&bar[1], __ATOMIC_ACQUIRE, __HIP_MEMORY_SCOPE_AGENT) == gen)
        __builtin_amdgcn_s_sleep(1);
    }
    __threadfence();   // acquire side
  }
  __syncthreads();
}

// Z partials layout: [b][col][ks], ks stride 1 (NKS=8) -> 2 coalesced float4 per value
__device__ __forceinline__ float zget(const float* __restrict__ Zp, int b, int col, int ncols){
  const float* p = Zp + (((size_t)b * ncols + col) << 3);
  float4 u0 = *(const float4*)p;
  float4 u1 = *(const float4*)(p + 4);
  double s = (double)u0.x + (double)u0.y + (double)u0.z + (double)u0.w
           + (double)u1.x + (double)u1.y + (double)u1.z + (double)u1.w;
  return (float)s;
}

// ---------------- zero ----------------
__global__ void kzerod(double* p, int n){
  int i = blockIdx.x * 256 + threadIdx.x;
  if (i < n) p[i] = 0.0;
}
__global__ void kzerof(float* p, int n){
  int i = blockIdx.x * 256 + threadIdx.x;
  if (i < n) p[i] = 0.f;
}

// ---------------- pack weights: WT[c][j] ----------------
__global__ void kprep(const float* __restrict__ W_all, const float* __restrict__ W_d,
                      const float* __restrict__ U_all, float* __restrict__ WT)
{
  int i = blockIdx.x * 256 + threadIdx.x;
  const int nWT = NH * NZCOL;
  if (i >= nWT) return;
  int c = i / NZCOL, j = i % NZCOL;
  float v;
  if (j < NG4){ int g = j / NH, r = j % NH; v = W_all[r * 1536 + g * NH + c]; }
  else if (j < 1920){ int r = j - NG4; v = W_d[r * NH + c]; }
  else { int jj = j - 1920; int g = jj / NH, r = jj % NH; v = U_all[(g * NH + r) * NH + c]; }
  WT[i] = v;
}

// ---------------- one-time Q GEMM (unchanged) ----------------
__global__ __launch_bounds__(256) void kqgemm(const float* __restrict__ X,
    const float* __restrict__ Bw, float* __restrict__ Q)
{
  int j0 = blockIdx.x * 64, i0 = blockIdx.y * 64;
  __shared__ __align__(16) float As[32][68];
  __shared__ __align__(16) float Bs[32][64];
  int tid = threadIdx.x;
  int tn = tid & 15, tm = tid >> 4;
  int slm = tid >> 2;
  int slc = (tid & 3) * 8;
  int blk = tid >> 3;
  int bln = (tid & 7) * 8;
  double accd[4][4] = {{0.0}};
  const float* arow = X + (size_t)(i0 + slm) * NH;
  for (int c0 = 0; c0 < NH; c0 += 32){
    float4 a4 = *(const float4*)(arow + c0 + slc);
    float4 a4b = *(const float4*)(arow + c0 + slc + 4);
    As[slc+0][slm] = a4.x;  As[slc+1][slm] = a4.y;
    As[slc+2][slm] = a4.z;  As[slc+3][slm] = a4.w;
    As[slc+4][slm] = a4b.x; As[slc+5][slm] = a4b.y;
    As[slc+6][slm] = a4b.z; As[slc+7][slm] = a4b.w;
    const float* bp = Bw + (size_t)(c0 + blk) * NZCOL + j0 + bln;
    float4 b4a = *(const float4*)bp;
    float4 b4b = *(const float4*)(bp + 4);
    *(float4*)&Bs[blk][bln] = b4a;
    *(float4*)&Bs[blk][bln+4] = b4b;
    __syncthreads();
    float acc[4][4] = {{0.f}};
    #pragma unroll 8
    for (int c = 0; c < 32; ++c){
      float4 av = *(const float4*)&As[c][tm*4];
      float4 bv = *(const float4*)&Bs[c][tn*4];
      float a[4] = {av.x, av.y, av.z, av.w};
      float bb[4] = {bv.x, bv.y, bv.z, bv.w};
      #pragma unroll
      for (int mm = 0; mm < 4; ++mm)
        #pragma unroll
        for (int jj = 0; jj < 4; ++jj)
          acc[mm][jj] += a[mm] * bb[jj];
    }
    __syncthreads();
    #pragma unroll
    for (int mm = 0; mm < 4; ++mm)
      #pragma unroll
      for (int jj = 0; jj < 4; ++jj) accd[mm][jj] += (double)acc[mm][jj];
  }
  #pragma unroll
  for (int mm = 0; mm < 4; ++mm){
    float4 o; o.x = (float)accd[mm][0]; o.y = (float)accd[mm][1];
    o.z = (float)accd[mm][2]; o.w = (float)accd[mm][3];
    *(float4*)(Q + (size_t)(i0 + tm*4 + mm) * 1536 + j0 + tn*4) = o;
  }
}

// ================= fused recurrent loop (persistent, plain launch) =================
__global__ __launch_bounds__(256, 1) void kloop(
    const float* __restrict__ WT, float* __restrict__ Hs, float* __restrict__ CCs,
    const float* __restrict__ xin, const float* __restrict__ tstamps,
    const float* __restrict__ qsrc, unsigned long long q_bs, unsigned long long q_ts,
    int qfromZ, float* __restrict__ Zp, float* __restrict__ ctx,
    int ncols, unsigned* bar)
{
  __shared__ __align__(16) float As[KSL][72];    // [k][m], 64 rows + pad
  __shared__ __align__(16) float Bs[KSL][132];   // [k][j], 128 cols + pad
  const int tid = threadIdx.x;
  const int njt = ncols >> 7;                    // 128-wide j tiles: 15 or 27
  const int ntasks = njt * 2 * NKS;              // j x m(64) x ks(48)
  const bool persist = (ntasks <= GBLK);         // B-tile persists in LDS across t
  const int tn = tid & 15, tm = tid >> 4;        // j = tn*8, m = tm*4
  const int wv = tid >> 6, ln = tid & 63;
  const int bnl = (blockIdx.x << 2) + wv;        // NL row

  float hreg[6], creg[6];
  #pragma unroll
  for (int i = 0; i < 6; ++i){ hreg[i] = 0.f; creg[i] = 0.f; }

  for (int t = 0; t < NS; ++t){
    // ---------------- GEMM phase: Z partials ----------------
    for (int task = blockIdx.x; task < ntasks; task += GBLK){
      const int jt = task % njt;
      const int mt = (task / njt) & 1;
      const int ks = task / (njt << 1);
      const int j0 = jt << 7, m0 = mt << 6, c0 = ks * KSL;
      if (t == 0 || !persist){
        #pragma unroll
        for (int v = 0; v < 6; ++v){
          int id = tid + (v << 8);
          int kr = id >> 5, jc = (id & 31) << 2;
          *(float4*)&Bs[kr][jc] = *(const float4*)(WT + (size_t)(c0 + kr) * NZCOL + j0 + jc);
        }
      }
      {
        int row = tid >> 2, kb = (tid & 3) * 12;
        const float* ar;
        if (jt < 12)      ar = Hs  + (size_t)(m0 + row) * NH + c0 + kb;
        else if (jt < 15) ar = CCs + (size_t)(m0 + row) * NH + c0 + kb;
        else              ar = xin + ((size_t)(m0 + row) * NS + t) * NH + c0 + kb;
        float4 a0 = *(const float4*)ar;
        float4 a1 = *(const float4*)(ar + 4);
        float4 a2 = *(const float4*)(ar + 8);
        As[kb+ 0][row] = a0.x; As[kb+ 1][row] = a0.y; As[kb+ 2][row] = a0.z; As[kb+ 3][row] = a0.w;
        As[kb+ 4][row] = a1.x; As[kb+ 5][row] = a1.y; As[kb+ 6][row] = a1.z; As[kb+ 7][row] = a1.w;
        As[kb+ 8][row] = a2.x; As[kb+ 9][row] = a2.y; As[kb+10][row] = a2.z; As[kb+11][row] = a2.w;
      }
      __syncthreads();
      float acc[4][8];
      #pragma unroll
      for (int mm = 0; mm < 4; ++mm)
        #pragma unroll
        for (int jj = 0; jj < 8; ++jj) acc[mm][jj] = 0.f;
      #pragma unroll 4
      for (int c = 0; c < KSL; ++c){
        const float4 av = *(const float4*)&As[c][tm << 2];
        const float4 b0 = *(const float4*)&Bs[c][tn << 3];
        const float4 b1 = *(const float4*)&Bs[c][(tn << 3) + 4];
        const float aa[4] = {av.x, av.y, av.z, av.w};
        const float bb[8] = {b0.x, b0.y, b0.z, b0.w, b1.x, b1.y, b1.z, b1.w};
        #pragma unroll
        for (int mm = 0; mm < 4; ++mm)
          #pragma unroll
          for (int jj = 0; jj < 8; ++jj) acc[mm][jj] += aa[mm] * bb[jj];
      }
      #pragma unroll
      for (int mm = 0; mm < 4; ++mm){
        float* zr = Zp + (((size_t)(m0 + (tm << 2) + mm) * ncols + (j0 + (tn << 3))) << 3) + ks;
        #pragma unroll
        for (int jj = 0; jj < 8; ++jj) zr[(size_t)jj << 3] = acc[mm][jj];
      }
      __syncthreads();
    }
    gridbar(bar);

    // ---------------- NL phase: one wave per batch row ----------------
    if (bnl < NB){
      const int b = bnl;
      const float* qb = qsrc + (size_t)b * q_bs + (size_t)t * q_ts;
      double ts = (double)tstamps[b * NS + t];
      float tsf = (float)ts;

      float cc6[6], mv6[6];
      double s_cc = 0, s_h = 0, s_mv = 0, s_x = 0;
      #pragma unroll
      for (int i = 0; i < 6; ++i){
        int r = ln + (i << 6);
        float c_ = creg[i]; cc6[i] = c_; s_cc += (double)c_ * c_;
        float h_ = hreg[i]; s_h += (double)h_ * h_;
        float m_ = zget(Zp, b, NG4 + r, ncols); mv6[i] = m_; s_mv += (double)m_ * m_;
        float x_ = xin[((size_t)b * NS + t) * NH + r]; s_x += (double)x_ * x_;
      }
      // hoisted gate operand loads (overlap latency with the scalar chain below)
      float pgall[4][6], qgall[4][6];
      #pragma unroll
      for (int g = 0; g < 4; ++g){
        #pragma unroll
        for (int i = 0; i < 6; ++i){
          int r = ln + (i << 6);
          pgall[g][i] = zget(Zp, b, g * NH + r, ncols);
          qgall[g][i] = qfromZ ? zget(Zp, b, 1920 + g * NH + r, ncols) : qb[g * NH + r];
        }
      }
      double cc2 = wredsumd(s_cc);  double cn = normclip(cc2);
      double hn  = normclip(wredsumd(s_h));
      double mvn = normclip(wredsumd(s_mv));
      double xn  = normclip(wredsumd(s_x));

      // ---- c path ----
      double s1 = tanh(mvn / cn * artanh_(cn));
      float c1f = (float)(s1 / mvn);
      float m1[6]; double sm1 = 0;
      #pragma unroll
      for (int i = 0; i < 6; ++i){ m1[i] = c1f * mv6[i]; sm1 += (double)m1[i] * m1[i]; }
      double n1 = normclip(wredsumd(sm1));
      float l1f = (float)(artanh_(n1) / n1);
      float v6[6]; double sv = 0;
      #pragma unroll
      for (int i = 0; i < 6; ++i){ v6[i] = tanhf(l1f * m1[i]); sv += (double)v6[i] * v6[i]; }
      double nv = normclip(wredsumd(sv));
      float e1f = (float)(tanh(nv) / nv);
      float cs1[6]; double scs = 0, sccd = 0;
      #pragma unroll
      for (int i = 0; i < 6; ++i){ cs1[i] = e1f * v6[i]; scs += (double)cs1[i] * cs1[i]; sccd -= (double)cs1[i] * cc6[i]; }

      double xnt = sqrt(fmax(384.0 * ts * ts, 1e-15));
      double swx = 0;
      #pragma unroll
      for (int i = 0; i < 6; ++i){ float w = cs1[i] * tsf; swx += (double)w * w; }
      double wxn1 = normclip(wredsumd(swx));
      double s2c = tanh(wxn1 / xnt * artanh_(xnt)) / wxn1;
      float s2f = (float)(s2c * ts);
      float cs2[6];
      #pragma unroll
      for (int i = 0; i < 6; ++i) cs2[i] = s2f * cs1[i];

      double x2a = wredsumd(scs);
      double xya = wredsumd(sccd);
      double y2a = cc2;
      double dA = fmax(1.0 + 2.0 * xya + x2a * y2a, 1e-15);
      float fXA = (float)((1.0 + 2.0 * xya + y2a) / dA);
      float fYA = (float)((1.0 - x2a) / dA);
      float A6[6]; double sA = 0, sAc = 0, sc2 = 0;
      #pragma unroll
      for (int i = 0; i < 6; ++i){
        A6[i] = fXA * (-cs1[i]) + fYA * cc6[i];
        sA += (double)A6[i] * A6[i]; sAc += (double)A6[i] * cs2[i]; sc2 += (double)cs2[i] * cs2[i];
      }
      double x2b = wredsumd(sA), xyb = wredsumd(sAc), y2b = wredsumd(sc2);
      double dB = fmax(1.0 + 2.0 * xyb + x2b * y2b, 1e-15);
      float fXB = (float)((1.0 + 2.0 * xyb + y2b) / dB);
      float fYB = (float)((1.0 - x2b) / dB);
      float cadj[6];
      #pragma unroll
      for (int i = 0; i < 6; ++i) cadj[i] = fXB * A6[i] + fYB * cs2[i];

      // ---- gates ----
      double art_hn = artanh_(hn), art_xn = artanh_(xn);
      float gates[4][6];
      for (int g = 0; g < 4; ++g){
        float pg[6], qg[6]; double s_p = 0, s_q = 0;
        #pragma unroll
        for (int i = 0; i < 6; ++i){
          pg[i] = pgall[g][i]; s_p += (double)pg[i] * pg[i];
          qg[i] = qgall[g][i]; s_q += (double)qg[i] * qg[i];
        }
        double pn = normclip(wredsumd(s_p));
        double qn = normclip(wredsumd(s_q));
        float saf = (float)(tanh(pn / hn * art_hn) / pn);
        float sbf = (float)(tanh(qn / xn * art_xn) / qn);
        float a6[6], b6[6]; double sx2 = 0, sy2 = 0, sxy = 0;
        #pragma unroll
        for (int i = 0; i < 6; ++i){
          a6[i] = saf * pg[i]; b6[i] = sbf * qg[i];
          sx2 += (double)a6[i] * a6[i]; sy2 += (double)b6[i] * b6[i]; sxy += (double)a6[i] * b6[i];
        }
        sx2 = wredsumd(sx2); sy2 = wredsumd(sy2); sxy = wredsumd(sxy);
        double dd = fmax(1.0 + 2.0 * sxy + sx2 * sy2, 1e-15);
        float fX = (float)((1.0 + 2.0 * sxy + sy2) / dd);
        float fY = (float)((1.0 - sx2) / dd);
        float m6[6]; double smm = 0;
        #pragma unroll
        for (int i = 0; i < 6; ++i){ m6[i] = fX * a6[i] + fY * b6[i]; smm += (double)m6[i] * m6[i]; }
        double nm = normclip(wredsumd(smm));
        float slf = (float)(artanh_(nm) / nm);
        #pragma unroll
        for (int i = 0; i < 6; ++i) gates[g][i] = 1.f / (1.f + expf(-slf * m6[i]));
      }

      // ---- cc_n, h_n ----
      double sct = 0, sict = 0; float wP[6];
      #pragma unroll
      for (int i = 0; i < 6; ++i){ float ct = gates[3][i]; sct += (double)ct * ct; wP[i] = gates[1][i] * ct; sict += (double)wP[i] * wP[i]; }
      double ctn = normclip(wredsumd(sct));
      double wPn = normclip(wredsumd(sict));
      float sPf = (float)(tanh(wPn / ctn * artanh_(ctn)) / wPn);
      float P6[6]; double sPP = 0;
      #pragma unroll
      for (int i = 0; i < 6; ++i){ P6[i] = sPf * wP[i]; sPP += (double)P6[i] * P6[i]; }
      double sca = 0, sfca = 0; float wQ[6];
      #pragma unroll
      for (int i = 0; i < 6; ++i){ sca += (double)cadj[i] * cadj[i]; wQ[i] = gates[0][i] * cadj[i]; sfca += (double)wQ[i] * wQ[i]; }
      double can = normclip(wredsumd(sca));
      double wQn = normclip(wredsumd(sfca));
      float sQf = (float)(tanh(wQn / can * artanh_(can)) / wQn);
      float Q6[6]; double sQQ = 0, sPQ = 0;
      #pragma unroll
      for (int i = 0; i < 6; ++i){ Q6[i] = sQf * wQ[i]; sQQ += (double)Q6[i] * Q6[i]; sPQ += (double)P6[i] * Q6[i]; }
      double x2c = wredsumd(sPP), y2c = wredsumd(sQQ), xyc = wredsumd(sPQ);
      double dC = fmax(1.0 + 2.0 * xyc + x2c * y2c, 1e-15);
      float fXC = (float)((1.0 + 2.0 * xyc + y2c) / dC);
      float fYC = (float)((1.0 - x2c) / dC);
      float ccn6[6], w6[6]; double sw_ = 0;
      #pragma unroll
      for (int i = 0; i < 6; ++i){ ccn6[i] = fXC * P6[i] + fYC * Q6[i]; w6[i] = tanhf(ccn6[i]); sw_ += (double)w6[i] * w6[i]; }
      double nw = normclip(wredsumd(sw_));
      float eef = (float)(tanh(nw) / nw);
      float e6[6], wH[6]; double se = 0, soe = 0;
      #pragma unroll
      for (int i = 0; i < 6; ++i){ e6[i] = eef * w6[i]; se += (double)e6[i] * e6[i]; wH[i] = gates[2][i] * e6[i]; soe += (double)wH[i] * wH[i]; }
      double en = normclip(wredsumd(se));
      double wHn = normclip(wredsumd(soe));
      float sHf = (float)(tanh(wHn / en * artanh_(en)) / wHn);
      #pragma unroll
      for (int i = 0; i < 6; ++i){
        int r = ln + (i << 6);
        float hv = sHf * wH[i];
        creg[i] = ccn6[i]; hreg[i] = hv;
        CCs[b * NH + r] = ccn6[i];
        Hs[b * NH + r] = hv;
        ctx[((size_t)b * NS + t) * NH + r] = gates[2][i];
      }
    }
    gridbar(bar);
  }
}

// ================= legacy per-step kernels (fallback if persistence unsafe) =================
__global__ __launch_bounds__(256) void kgemm(const float* __restrict__ WT,
    const float* __restrict__ Hs, const float* __restrict__ CCs,
    const float* __restrict__ xin, float* __restrict__ Z, int zstride, int t)
{
  int j0 = blockIdx.x * 64;
  int m0 = blockIdx.y * 32;
  __shared__ __align__(16) float As[32][36];
  __shared__ __align__(16) float Bs[32][64];
  int tid = threadIdx.x;
  int tn = tid & 15;
  int tm = tid >> 4;
  int slm = tid >> 3;
  int slc = (tid & 7) * 4;
  int blk = tid >> 3;
  int bln = (tid & 7) * 8;
  double accd[2][4] = {{0.0}};
  int gm = m0 + slm;
  const float* arow;
  if (j0 < NG4)       arow = Hs  + (size_t)gm * NH;
  else if (j0 < 1920) arow = CCs + (size_t)gm * NH;
  else                arow = xin + ((size_t)gm * NS + t) * NH;
  for (int c0 = 0; c0 < NH; c0 += 32){
    float4 a4 = *(const float4*)(arow + c0 + slc);
    As[slc+0][slm] = a4.x; As[slc+1][slm] = a4.y;
    As[slc+2][slm] = a4.z; As[slc+3][slm] = a4.w;
    const float* bp = WT + (size_t)(c0 + blk) * NZCOL + j0 + bln;
    float4 b4a = *(const float4*)bp;
    float4 b4b = *(const float4*)(bp + 4);
    *(float4*)&Bs[blk][bln] = b4a;
    *(float4*)&Bs[blk][bln+4] = b4b;
    __syncthreads();
    float acc[2][4] = {{0.f}};
    #pragma unroll 8
    for (int c = 0; c < 32; ++c){
      float2 a2 = *(const float2*)&As[c][tm*2];
      float4 bv = *(const float4*)&Bs[c][tn*4];
      acc[0][0] += a2.x * bv.x; acc[0][1] += a2.x * bv.y;
      acc[0][2] += a2.x * bv.z; acc[0][3] += a2.x * bv.w;
      acc[1][0] += a2.y * bv.x; acc[1][1] += a2.y * bv.y;
      acc[1][2] += a2.y * bv.z; acc[1][3] += a2.y * bv.w;
    }
    __syncthreads();
    #pragma unroll
    for (int mm = 0; mm < 2; ++mm)
      #pragma unroll
      for (int jj = 0; jj < 4; ++jj) accd[mm][jj] += (double)acc[mm][jj];
  }
  #pragma unroll
  for (int mm = 0; mm < 2; ++mm){
    float4 o; o.x = (float)accd[mm][0]; o.y = (float)accd[mm][1];
    o.z = (float)accd[mm][2]; o.w = (float)accd[mm][3];
    *(float4*)(Z + (size_t)(m0 + tm*2 + mm) * zstride + j0 + tn*4) = o;
  }
}

__global__ __launch_bounds__(256) void knl(const float* __restrict__ Z, int zstride,
    const float* __restrict__ qsrc, unsigned long long q_bs, unsigned long long q_ts,
    float* __restrict__ Hs, float* __restrict__ CCs, float* __restrict__ ctx,
    const float* __restrict__ xin, const float* __restrict__ tstamps, int t)
{
  int wv = threadIdx.x >> 6, ln = threadIdx.x & 63;
  int b = blockIdx.x * 4 + wv;
  const float* zb = Z + (size_t)b * zstride;
  const float* qb = qsrc + (size_t)b * q_bs + (size_t)t * q_ts;
  double ts = (double)tstamps[b * NS + t];
  float tsf = (float)ts;

  float cc6[6], mv6[6];
  double s_cc = 0, s_h = 0, s_mv = 0, s_x = 0;
  #pragma unroll
  for (int i = 0; i < 6; ++i){
    int r = ln + 64 * i;
    float c_ = CCs[b * NH + r]; cc6[i] = c_; s_cc += (double)c_ * c_;
    float h_ = Hs[b * NH + r];  s_h += (double)h_ * h_;
    float m_ = zb[NG4 + r];     mv6[i] = m_; s_mv += (double)m_ * m_;
    float x_ = xin[((size_t)b * NS + t) * NH + r]; s_x += (double)x_ * x_;
  }
  double cc2 = wredsumd(s_cc);  double cn = normclip(cc2);
  double hn  = normclip(wredsumd(s_h));
  double mvn = normclip(wredsumd(s_mv));
  double xn  = normclip(wredsumd(s_x));

  double s1 = tanh(mvn / cn * artanh_(cn));
  float c1f = (float)(s1 / mvn);
  float m1[6]; double sm1 = 0;
  #pragma unroll
  for (int i = 0; i < 6; ++i){ m1[i] = c1f * mv6[i]; sm1 += (double)m1[i] * m1[i]; }
  double n1 = normclip(wredsumd(sm1));
  float l1f = (float)(artanh_(n1) / n1);
  float v6[6]; double sv = 0;
  #pragma unroll
  for (int i = 0; i < 6; ++i){ v6[i] = tanhf(l1f * m1[i]); sv += (double)v6[i] * v6[i]; }
  double nv = normclip(wredsumd(sv));
  float e1f = (float)(tanh(nv) / nv);
  float cs1[6]; double scs = 0, sccd = 0;
  #pragma unroll
  for (int i = 0; i < 6; ++i){ cs1[i] = e1f * v6[i]; scs += (double)cs1[i] * cs1[i]; sccd -= (double)cs1[i] * cc6[i]; }

  double xnt = sqrt(fmax(384.0 * ts * ts, 1e-15));
  double swx = 0;
  #pragma unroll
  for (int i = 0; i < 6; ++i){ float w = cs1[i] * tsf; swx += (double)w * w; }
  double wxn1 = normclip(wredsumd(swx));
  double s2c = tanh(wxn1 / xnt * artanh_(xnt)) / wxn1;
  float s2f = (float)(s2c * ts);
  float cs2[6];
  #pragma unroll
  for (int i = 0; i < 6; ++i) cs2[i] = s2f * cs1[i];

  double x2a = wredsumd(scs);
  double xya = wredsumd(sccd);
  double y2a = cc2;
  double dA = fmax(1.0 + 2.0 * xya + x2a * y2a, 1e-15);
  float fXA = (float)((1.0 + 2.0 * xya + y2a) / dA);
  float fYA = (float)((1.0 - x2a) / dA);
  float A6[6]; double sA = 0, sAc = 0, sc2 = 0;
  #pragma unroll
  for (int i = 0; i < 6; ++i){
    A6[i] = fXA * (-cs1[i]) + fYA * cc6[i];
    sA += (double)A6[i] * A6[i]; sAc += (double)A6[i] * cs2[i]; sc2 += (double)cs2[i] * cs2[i];
  }
  double x2b = wredsumd(sA), xyb = wredsumd(sAc), y2b = wredsumd(sc2);
  double dB = fmax(1.0 + 2.0 * xyb + x2b * y2b, 1e-15);
  float fXB = (float)((1.0 + 2.0 * xyb + y2b) / dB);
  float fYB = (float)((1.0 - x2b) / dB);
  float cadj[6];
  #pragma unroll
  for (int i = 0; i < 6; ++i) cadj[i] = fXB * A6[i] + fYB * cs2[i];

  double art_hn = artanh_(hn), art_xn = artanh_(xn);
  float gates[4][6];
  for (int g = 0; g < 4; ++g){
    float pg[6], qg[6]; double s_p = 0, s_q = 0;
    #pragma unroll
    for (int i = 0; i < 6; ++i){
      int r = ln + 64 * i;
      pg[i] = zb[g * NH + r];       s_p += (double)pg[i] * pg[i];
      qg[i] = qb[g * NH + r];       s_q += (double)qg[i] * qg[i];
    }
    double pn = normclip(wredsumd(s_p));
    double qn = normclip(wredsumd(s_q));
    float saf = (float)(tanh(pn / hn * art_hn) / pn);
    float sbf = (float)(tanh(qn / xn * art_xn) / qn);
    float a6[6], b6[6]; double sx2 = 0, sy2 = 0, sxy = 0;
    #pragma unroll
    for (int i = 0; i < 6; ++i){
      a6[i] = saf * pg[i]; b6[i] = sbf * qg[i];
      sx2 += (double)a6[i] * a6[i]; sy2 += (double)b6[i] * b6[i]; sxy += (double)a6[i] * b6[i];
    }
    sx2 = wredsumd(sx2); sy2 = wredsumd(sy2); sxy = wredsumd(sxy);
    double dd = fmax(1.0 + 2.0 * sxy + sx2 * sy2, 1e-15);
    float fX = (float)((1.0 + 2.0 * sxy + sy2) / dd);
    float fY = (float)((1.0 - sx2) / dd);
    float m6[6]; double smm = 0;
    #pragma unroll
    for (int i = 0; i < 6; ++i){ m6[i] = fX * a6[i] + fY * b6[i]; smm += (double)m6[i] * m6[i]; }
    double nm = normclip(wredsumd(smm));
    float slf = (float)(artanh_(nm) / nm);
    #pragma unroll
    for (int i = 0; i < 6; ++i) gates[g][i] = 1.f / (1.f + expf(-slf * m6[i]));
  }

  double sct = 0, sict = 0; float wP[6];
  #pragma unroll
  for (int i = 0; i < 6; ++i){ float ct = gates[3][i]; sct += (double)ct * ct; wP[i] = gates[1][i] * ct; sict += (double)wP[i] * wP[i]; }
  double ctn = normclip(wredsumd(sct));
  double wPn = normclip(wredsumd(sict));
  float sPf = (float)(tanh(wPn / ctn * artanh_(ctn)) / wPn);
  float P6[6]; double sPP = 0;
  #pragma unroll
  for (int i = 0; i < 6; ++i){ P6[i] = sPf * wP[i]; sPP += (double)P6[i] * P6[i]; }
  double sca = 0, sfca = 0; float wQ[6];
  #pragma unroll
  for (int i = 0; i < 6; ++i){ sca += (double)cadj[i] * cadj[i]; wQ[i] = gates[0][i] * cadj[i]; sfca += (double)wQ[i] * wQ[i]; }
  double can = normclip(wredsumd(sca));
  double wQn = normclip(wredsumd(sfca));
  float sQf = (float)(tanh(wQn / can * artanh_(can)) / wQn);
  float Q6[6]; double sQQ = 0, sPQ = 0;
  #pragma unroll
  for (int i = 0; i < 6; ++i){ Q6[i] = sQf * wQ[i]; sQQ += (double)Q6[i] * Q6[i]; sPQ += (double)P6[i] * Q6[i]; }
  double x2c = wredsumd(sPP), y2c = wredsumd(sQQ), xyc = wredsumd(sPQ);
  double dC = fmax(1.0 + 2.0 * xyc + x2c * y2c, 1e-15);
  float fXC = (float)((1.0 + 2.0 * xyc + y2c) / dC);
  float fYC = (float)((1.0 - x2c) / dC);
  float ccn6[6], w6[6]; double sw_ = 0;
  #pragma unroll
  for (int i = 0; i < 6; ++i){ ccn6[i] = fXC * P6[i] + fYC * Q6[i]; w6[i] = tanhf(ccn6[i]); sw_ += (double)w6[i] * w6[i]; }
  double nw = normclip(wredsumd(sw_));
  float eef = (float)(tanh(nw) / nw);
  float e6[6], wH[6]; double se = 0, soe = 0;
  #pragma unroll
  for (int i = 0; i < 6; ++i){ e6[i] = eef * w6[i]; se += (double)e6[i] * e6[i]; wH[i] = gates[2][i] * e6[i]; soe += (double)wH[i] * wH[i]; }
  double en = normclip(wredsumd(se));
  double wHn = normclip(wredsumd(soe));
  float sHf = (float)(tanh(wHn / en * artanh_(en)) / wHn);
  #pragma unroll
  for (int i = 0; i < 6; ++i){
    int r = ln + 64 * i;
    CCs[b * NH + r] = ccn6[i];
    Hs[b * NH + r] = sHf * wH[i];
    ctx[((size_t)b * NS + t) * NH + r] = gates[2][i];
  }
}

// ---------------- block reduce helpers ----------------
__device__ __forceinline__ double blocksumd(double v, double* red){
  v = wredsumd(v);
  __syncthreads();
  if ((threadIdx.x & 63) == 0) red[threadIdx.x >> 6] = v;
  __syncthreads();
  return red[0] + red[1] + red[2] + red[3];
}
__device__ __forceinline__ double blockmaxd(double v, double* red){
  #pragma unroll
  for (int off = 32; off; off >>= 1) v = fmax(v, __shfl_xor(v, off, 64));
  __syncthreads();
  if ((threadIdx.x & 63) == 0) red[threadIdx.x >> 6] = v;
  __syncthreads();
  return fmax(fmax(red[0], red[1]), fmax(red[2], red[3]));
}

// ---------------- query / scores / softmax / aw / bt ----------------
__global__ __launch_bounds__(256) void kattn1(const float* __restrict__ Hs,
    const float* __restrict__ Win, const float* __restrict__ ctx,
    const float* __restrict__ dt, const float* __restrict__ ab,
    double* __restrict__ query, double* __restrict__ aw, double* __restrict__ bt)
{
  int b = blockIdx.x; int tid = threadIdx.x;
  __shared__ double hL[NH], qL[NH], sc[NS];
  __shared__ double red[4];
  for (int r = tid; r < NH; r += 256) hL[r] = (double)Hs[b * NH + r];
  __syncthreads();
  for (int r = tid; r < NH; r += 256){
    double s = 0;
    const float* wr = Win + (size_t)r * NH;
    for (int c = 0; c < NH; ++c) s += hL[c] * (double)wr[c];
    qL[r] = s; query[b * NH + r] = s;
  }
  __syncthreads();
  int wv = tid >> 6, ln = tid & 63;
  for (int s_ = wv; s_ < NS; s_ += 4){
    const float* crow = ctx + ((size_t)b * NS + s_) * NH;
    double par = 0;
    #pragma unroll
    for (int i = 0; i < 6; ++i){ int d = ln + 64 * i; par += qL[d] * (double)crow[d]; }
    par = wredsumd(par);
    if (ln == 0) sc[s_] = par;
  }
  __syncthreads();
  double v0 = sc[tid];
  double v1 = (tid + 256 < NS) ? sc[tid + 256] : -1e300;
  double mx = blockmaxd(fmax(v0, v1), red);
  double e0 = exp(v0 - mx);
  double e1 = (tid + 256 < NS) ? exp(v1 - mx) : 0.0;
  double tot = blocksumd(e0 + e1, red);
  double a0 = e0 / tot, a1 = e1 / tot;
  double n = normclip(blocksumd(a0 * a0 + a1 * a1, red));
  double s1 = tanh(n) / n;
  double w0 = s1 * a0, w1 = s1 * a1;
  double pn = normclip(blocksumd(w0 * w0 + w1 * w1, red));
  if (pn > 0.999){ double f = 0.999 / pn; w0 *= f; w1 *= f; }
  aw[b * NS + tid] = w0;
  if (tid + 256 < NS) aw[b * NS + tid + 256] = w1;
  double abv = (double)ab[b];
  double b0 = exp(-abv * (double)dt[b * NS + tid]);
  double b1v = (tid + 256 < NS) ? exp(-abv * (double)dt[b * NS + tid + 256]) : 0.0;
  double nb = normclip(blocksumd(b0 * b0 + b1v * b1v, red));
  double sb = tanh(nb) / nb;
  double c0 = sb * b0, c1 = sb * b1v;
  double pnb = normclip(blocksumd(c0 * c0 + c1 * c1, red));
  if (pnb > 0.999){ double f = 0.999 / pnb; c0 *= f; c1 *= f; }
  bt[b * NS + tid] = c0;
  if (tid + 256 < NS) bt[b * NS + tid + 256] = c1;
}

// ---------------- hyperbolic attention mixing ----------------
__global__ __launch_bounds__(256) void kmix(const float* __restrict__ ctx,
    const double* __restrict__ aw, const double* __restrict__ bt,
    const float* __restrict__ ae, double* __restrict__ nom, double* __restrict__ den)
{
  int b = blockIdx.y; int h0 = blockIdx.x * 32;
  __shared__ float T[32][385];
  int tid = threadIdx.x;
  for (int idx = tid; idx < NS * 32; idx += 256){
    int s = idx >> 5, hh = idx & 31;
    T[hh][s] = ctx[((size_t)b * NS + s) * NH + h0 + hh];
  }
  __syncthreads();
  int wv = tid >> 6, ln = tid & 63;
  double aev = (double)ae[b];
  double aw6[6], bt6[6]; double sbt = 0;
  #pragma unroll
  for (int i = 0; i < 6; ++i){
    aw6[i] = aw[b * NS + ln + 64 * i];
    bt6[i] = bt[b * NS + ln + 64 * i];
    sbt += bt6[i] * bt6[i];
  }
  double xnb = normclip(wredsumd(sbt));
  double art_xnb = artanh_(xnb);
  double denacc = 0.0;
  for (int k = 0; k < 8; ++k){
    int hh = wv * 8 + k;
    double v[6]; double sx = 0;
    #pragma unroll
    for (int i = 0; i < 6; ++i){ v[i] = (double)T[hh][ln + 64 * i]; sx += v[i] * v[i]; }
    double xnv = normclip(wredsumd(sx));
    double wx[6]; double swx = 0;
    #pragma unroll
    for (int i = 0; i < 6; ++i){ wx[i] = aw6[i] * v[i]; swx += wx[i] * wx[i]; }
    double wxn = normclip(wredsumd(swx));
    double s1 = tanh(wxn / xnv * artanh_(xnv)) / wxn;
    double mix[6]; double sm = 0;
    #pragma unroll
    for (int i = 0; i < 6; ++i){ mix[i] = s1 * wx[i]; sm += mix[i] * mix[i]; }
    double n1 = normclip(wredsumd(sm));
    if (n1 > 0.999){ double f = 0.999 / n1;
      #pragma unroll
      for (int i = 0; i < 6; ++i) mix[i] *= f; }
    double sm2 = 0;
    #pragma unroll
    for (int i = 0; i < 6; ++i) sm2 += mix[i] * mix[i];
    double xn2 = normclip(wredsumd(sm2));
    double wx2[6]; double sw2 = 0;
    #pragma unroll
    for (int i = 0; i < 6; ++i){ wx2[i] = aev * mix[i]; sw2 += wx2[i] * wx2[i]; }
    double wxn2 = normclip(wredsumd(sw2));
    double s2 = tanh(wxn2 / xn2 * artanh_(xn2)) / wxn2;
    double tmp[6]; double st = 0;
    #pragma unroll
    for (int i = 0; i < 6; ++i){ tmp[i] = s2 * wx2[i]; st += tmp[i] * tmp[i]; }
    double n2 = normclip(wredsumd(st));
    if (n2 > 0.999){ double f = 0.999 / n2;
      #pragma unroll
      for (int i = 0; i < 6; ++i) tmp[i] *= f; }
    double wx3[6]; double sw3 = 0;
    #pragma unroll
    for (int i = 0; i < 6; ++i){ wx3[i] = tmp[i] * bt6[i]; sw3 += wx3[i] * wx3[i]; }
    double wxn3 = normclip(wredsumd(sw3));
    double s3 = tanh(wxn3 / xnb * art_xnb) / wxn3;
    double t2[6]; double st2 = 0;
    #pragma unroll
    for (int i = 0; i < 6; ++i){ t2[i] = s3 * wx3[i]; st2 += t2[i] * t2[i]; }
    double n3 = normclip(wredsumd(st2));
    if (n3 > 0.999){ double f = 0.999 / n3;
      #pragma unroll
      for (int i = 0; i < 6; ++i) t2[i] *= f; }
    #pragma unroll
    for (int i = 0; i < 6; ++i) t2[i] = fmax(t2[i], 0.0);
    double sxx = 0, syy = 0, sxy = 0;
    #pragma unroll
    for (int i = 0; i < 6; ++i){ sxx += mix[i] * mix[i]; syy += t2[i] * t2[i]; sxy += mix[i] * t2[i]; }
    sxx = wredsumd(sxx); syy = wredsumd(syy); sxy = wredsumd(sxy);
    double dn = fmax(1.0 + 2.0 * sxy + sxx * syy, 1e-15);
    double ca = (1.0 + 2.0 * sxy + syy) / dn, cb = (1.0 - sxx) / dn;
    double m2[6]; double sm3 = 0;
    #pragma unroll
    for (int i = 0; i < 6; ++i){ m2[i] = ca * mix[i] + cb * t2[i]; sm3 += m2[i] * m2[i]; }
    double n4 = normclip(wredsumd(sm3));
    if (n4 > 0.999){ double f = 0.999 / n4;
      #pragma unroll
      for (int i = 0; i < 6; ++i) m2[i] *= f; }
    double snn = 0;
    #pragma unroll
    for (int i = 0; i < 6; ++i) snn += m2[i] * m2[i];
    snn = wredsumd(snn);
    double lam = 2.0 / fmax(1.0 - snn, 1e-15);
    #pragma unroll
    for (int i = 0; i < 6; ++i) atomicAdd(&nom[b * NS + ln + 64 * i], lam * m2[i]);
    if (ln == 0) denacc += lam - 1.0;
  }
  if (ln == 0) atomicAdd(&den[b], denacc);
}

// ---------------- midpoint + logmap0 + output head ----------------
__global__ __launch_bounds__(256) void kfinal(const double* __restrict__ nom,
    const double* __restrict__ den, const double* __restrict__ query,
    const float* __restrict__ Wout, const float* __restrict__ W1,
    const float* __restrict__ b1, const float* __restrict__ W2,
    const float* __restrict__ b2, float* __restrict__ out)
{
  int b = blockIdx.x; int tid = threadIdx.x;
  __shared__ double comb[768];
  __shared__ double att[NH];
  __shared__ double x1[NH];
  __shared__ double red[4];
  double dnb = fmax(den[b], 1e-10);
  double u0 = nom[b * NS + tid] / dnb;
  double u1 = (tid + 256 < NS) ? nom[b * NS + tid + 256] / dnb : 0.0;
  double n = normclip(blocksumd(u0 * u0 + u1 * u1, red));
  double sf = tanh(0.5 * artanh_(n)) / n;
  double f0 = sf * u0, f1 = sf * u1;
  double n2 = normclip(blocksumd(f0 * f0 + f1 * f1, red));
  double sl = artanh_(n2) / n2;
  comb[tid] = sl * f0;
  if (tid + 256 < NS) comb[tid + 256] = sl * f1;
  for (int r = tid; r < NH; r += 256) comb[NH + r] = query[b * NH + r];
  __syncthreads();
  for (int r = tid; r < NH; r += 256){
    double s = 0;
    const float* wr = Wout + (size_t)r * 768;
    for (int c = 0; c < 768; ++c) s += comb[c] * (double)wr[c];
    att[r] = tanh(s);
  }
  __syncthreads();
  for (int r = tid; r < NH; r += 256){
    double s = (double)b1[r];
    const float* wr = W1 + (size_t)r * NH;
    for (int c = 0; c < NH; ++c) s += att[c] * (double)wr[c];
    x1[r] = fmax(s, 0.0);
  }
  __syncthreads();
  double p0 = 0, p1 = 0;
  for (int c = tid; c < NH; c += 256){ p0 += x1[c] * (double)W2[c]; p1 += x1[c] * (double)W2[NH + c]; }
  p0 = blocksumd(p0, red);
  p1 = blocksumd(p1, red);
  if (tid == 0){ out[b * 2 + 0] = (float)(p0 + (double)b2[0]); out[b * 2 + 1] = (float)(p1 + (double)b2[1]); }
}

extern "C" void kernel_launch(void* const* d_in, const int* in_sizes, int n_in,
                              void* d_out, int out_size, void* d_ws, size_t ws_size,
                              hipStream_t stream)
{
  const float* inputs  = (const float*)d_in[0];
  const float* tstamps = (const float*)d_in[1];
  const float* delta_t = (const float*)d_in[2];
  const float* W_all   = (const float*)d_in[3];
  const float* U_all   = (const float*)d_in[4];
  const float* W_d     = (const float*)d_in[5];
  const float* Win     = (const float*)d_in[6];
  const float* Wout    = (const float*)d_in[7];
  const float* ae      = (const float*)d_in[8];
  const float* ab      = (const float*)d_in[9];
  const float* W1      = (const float*)d_in[10];
  const float* b1      = (const float*)d_in[11];
  const float* W2      = (const float*)d_in[12];
  const float* b2      = (const float*)d_in[13];
  float* out = (float*)d_out;

  // double region
  double* wd = (double*)d_ws;
  size_t od = 0;
  double* NOMD  = wd + od; od += (size_t)NB * NS;
  double* DEND  = wd + od; od += (size_t)NB;
  double* QUERY = wd + od; od += (size_t)NB * NH;
  double* AW    = wd + od; od += (size_t)NB * NS;
  double* BT    = wd + od; od += (size_t)NB * NS;
  unsigned* BAR = (unsigned*)(wd + od);           // 256 B barrier slab
  float* wf = (float*)((char*)(wd + od) + 256);
  size_t of = 0;
  float* WT   = wf + of; of += (size_t)NH * NZCOL;    // 1,327,104
  float* Hs32 = wf + of; of += (size_t)NB * NH;
  float* CCs32= wf + of; of += (size_t)NB * NH;
  float* CTX  = wf + of; of += (size_t)NB * NS * NH;  // 18,874,368
  float* Zp   = wf + of;                              // partials, sized by mode

  size_t base_bytes = od * 8 + 256 + of * 4;
  size_t zp_pre  = (size_t)NKS * NB * 1920 * 4;       // 7.9 MB
  size_t q_bytes = (size_t)NB * NS * 1536 * 4;        // 302 MB
  bool usePre = (ws_size >= base_bytes + zp_pre + q_bytes);
  int ncols = usePre ? 1920 : NZCOL;
  float* Qp = Zp + (size_t)NKS * NB * ncols;

  // Host-side co-residency validation for the persistent kernel (pure host
  // queries: capture-safe). If the device can't hold all GBLK blocks
  // simultaneously, fall back to the per-step path.
  static int persist_ok = -1;
  if (persist_ok < 0){
    int dev = 0, mp = 0, bpc = 0;
    hipError_t e1 = hipGetDevice(&dev);
    hipDeviceProp_t props;
    hipError_t e2 = (e1 == hipSuccess) ? hipGetDeviceProperties(&props, dev) : e1;
    if (e2 == hipSuccess) mp = props.multiProcessorCount;
    hipError_t e3 = hipOccupancyMaxActiveBlocksPerMultiprocessor(&bpc, kloop, 256, 0);
    persist_ok = (e2 == hipSuccess && e3 == hipSuccess && mp * bpc >= GBLK) ? 1 : 0;
  }

  // zero accumulators, states, barrier
  int nzd = NB * NS + NB;
  hipLaunchKernelGGL(kzerod, dim3((nzd + 255) / 256), dim3(256), 0, stream, NOMD, nzd);
  int nzf = NB * NH * 2;
  hipLaunchKernelGGL(kzerof, dim3((nzf + 255) / 256), dim3(256), 0, stream, Hs32, nzf);
  hipLaunchKernelGGL(kzerof, dim3(1), dim3(256), 0, stream, (float*)BAR, 64);

  int nprep = NH * NZCOL;
  hipLaunchKernelGGL(kprep, dim3((nprep + 255) / 256), dim3(256), 0, stream,
                     W_all, W_d, U_all, WT);

  const float* qsrc;
  unsigned long long q_bs, q_ts;
  int qfz;
  if (usePre){
    hipLaunchKernelGGL(kqgemm, dim3(24, 768), dim3(256), 0, stream, inputs, WT + 1920, Qp);
    qsrc = Qp; q_bs = (unsigned long long)NS * 1536ull; q_ts = 1536ull; qfz = 0;
  } else {
    qsrc = Zp; q_bs = 0ull; q_ts = 0ull; qfz = 1;
  }

  if (persist_ok == 1){
    // fused persistent recurrence (plain launch — graph-capture safe)
    hipLaunchKernelGGL(kloop, dim3(GBLK), dim3(256), 0, stream,
                       WT, Hs32, CCs32, inputs, tstamps,
                       qsrc, q_bs, q_ts, qfz, Zp, CTX, ncols, BAR);
  } else {
    // legacy per-step fallback (Zp doubles as the float Z buffer, stride ncols)
    const float* qsrc2 = usePre ? Qp : (Zp + 1920);
    unsigned long long qb2 = usePre ? (unsigned long long)NS * 1536ull : (unsigned long long)NZCOL;
    unsigned long long qt2 = usePre ? 1536ull : 0ull;
    for (int t = 0; t < NS; ++t){
      hipLaunchKernelGGL(kgemm, dim3(ncols / 64, 4), dim3(256), 0, stream,
                         WT, Hs32, CCs32, inputs, Zp, ncols, t);
      hipLaunchKernelGGL(knl, dim3(32), dim3(256), 0, stream,
                         Zp, ncols, qsrc2, qb2, qt2, Hs32, CCs32, CTX, inputs, tstamps, t);
    }
  }

  hipLaunchKernelGGL(kattn1, dim3(128), dim3(256), 0, stream,
                     Hs32, Win, CTX, delta_t, ab, QUERY, AW, BT);
  hipLaunchKernelGGL(kmix, dim3(12, 128), dim3(256), 0, stream, CTX, AW, BT, ae, NOMD, DEND);
  hipLaunchKernelGGL(kfinal, dim3(128), dim3(256), 0, stream,
                     NOMD, DEND, QUERY, Wout, W1, b1, W2, b2, out);
}